// Round 3
// baseline (1214.872 us; speedup 1.0000x reference)
//
#include <hip/hip_runtime.h>

typedef __attribute__((ext_vector_type(8))) short short8;
typedef __attribute__((ext_vector_type(4))) float f32x4;

#if __has_builtin(__builtin_amdgcn_exp2f)
#define EXP2F(x) __builtin_amdgcn_exp2f(x)
#else
#define EXP2F(x) exp2f(x)
#endif
#if __has_builtin(__builtin_amdgcn_rcpf)
#define RCPF(x) __builtin_amdgcn_rcpf(x)
#else
#define RCPF(x) (1.0f/(x))
#endif

// LDS layout (bytes):
//   x_lds  [64][400]  @0      25600   (bf16 [t][c], alive whole kernel)
//   qo_lds [64][80]   @25600   5120   (q during QKV/scores; o during PV/proj)
//   k_lds  [64][80]   @30720   5120
//   v_lds  [32][144]  @35840   4608   (vT: [d][t])
//   p_lds  [64][144]  @40448   9216
#define LDS_TOTAL 49664

__device__ __forceinline__ unsigned short f2bf(float f) {
    union { float f; unsigned u; } v; v.f = f;
    unsigned r = v.u + 0x7FFFu + ((v.u >> 16) & 1u);
    return (unsigned short)(r >> 16);
}
__device__ __forceinline__ unsigned pkbf(float lo, float hi) {
    return (unsigned)f2bf(lo) | ((unsigned)f2bf(hi) << 16);
}

// Pre-convert + permute weights: wqp[h*96 + j][c] with j: 0-31=q_d, 32-63=k_d, 64-95=v_d
__global__ void cvt_weights(const float* __restrict__ qw, const float* __restrict__ hw,
                            unsigned short* __restrict__ wqp, unsigned short* __restrict__ whc) {
    int i = blockIdx.x * 256 + threadIdx.x;
    if (i < 576 * 192) {
        int dr = i / 192, col = i % 192;
        int h = dr / 96, j = dr % 96;
        int src = (j < 32) ? h * 32 + j : (j < 64) ? 192 + h * 32 + (j - 32) : 384 + h * 32 + (j - 64);
        wqp[i] = f2bf(qw[src * 192 + col]);
    }
    if (i < 192 * 192) whc[i] = f2bf(hw[i]);
}

__global__ __launch_bounds__(256, 3) void wmha(
    const float* __restrict__ x, const float* __restrict__ qkv_b,
    const float* __restrict__ head_b, const unsigned short* __restrict__ wqp,
    const unsigned short* __restrict__ whc, float* __restrict__ out)
{
    extern __shared__ char smem[];
    char* const x_lds  = smem;
    char* const qo_lds = smem + 25600;
    char* const k_lds  = smem + 30720;
    char* const v_lds  = smem + 35840;
    char* const p_lds  = smem + 40448;

    const int tid = threadIdx.x;
    const int ln  = tid & 15;
    const int hi4 = (tid >> 4) & 3;
    const int wid = tid >> 6;

    const int bid  = blockIdx.x;
    const int widx = (bid & 7) * 1152 + (bid >> 3);   // bijective XCD swizzle (9216 % 8 == 0)
    const int b  = widx / 2304;
    const int rr = widx % 2304;
    const int oy = rr / 48, ox = rr % 48;
    const int row0 = oy * 8, col0 = ox * 8;

    // ---- stage x window -> LDS bf16 [t][c] ----
    {
        const int tok = tid & 63;
        const int qd  = tid >> 6;
        const int y = tok >> 3, xx = tok & 7;
        const float* gp = x + ((size_t)(b * 192) * 384 + (row0 + y)) * 384 + (col0 + xx);
        char* wp = x_lds + tok * 400 + qd * 96;
        #pragma unroll
        for (int kk = 0; kk < 12; ++kk) {
            const int c = qd * 48 + kk * 4;
            float f0 = gp[(size_t)(c + 0) * 147456];
            float f1 = gp[(size_t)(c + 1) * 147456];
            float f2 = gp[(size_t)(c + 2) * 147456];
            float f3 = gp[(size_t)(c + 3) * 147456];
            uint2 u;
            u.x = pkbf(f0, f1);
            u.y = pkbf(f2, f3);
            *(uint2*)(wp + kk * 8) = u;
        }
    }
    __syncthreads();

    // x B-frags for this wave's token tile (nt == wid): 6 frags, held in VGPRs
    short8 bx[6];
    #pragma unroll
    for (int kt = 0; kt < 6; ++kt)
        bx[kt] = *(const short8*)(x_lds + (wid * 16 + ln) * 400 + kt * 64 + hi4 * 16);

    // head-proj accumulators: wave owns c-tiles 3*wid..3*wid+2, all 4 token tiles
    f32x4 acc[3][4];
    #pragma unroll
    for (int mm = 0; mm < 3; ++mm)
        #pragma unroll
        for (int nt = 0; nt < 4; ++nt)
            acc[mm][nt] = (f32x4){0.f, 0.f, 0.f, 0.f};

    const float SC2 = 0.25503417f;  // (1/sqrt(32)) * log2(e)
    const int t = wid * 16 + ln;     // this wave's token rows for QKV stores

    for (int h = 0; h < 6; ++h) {
        // ---- per-head QKV: 6 m-tiles (0,1=q; 2,3=k; 4,5=v), token tile = wid ----
        #pragma unroll
        for (int mt = 0; mt < 6; ++mt) {
            const unsigned short* wr = wqp + ((h * 96 + mt * 16 + ln) * 192);
            f32x4 a = {0.f, 0.f, 0.f, 0.f};
            #pragma unroll
            for (int kt = 0; kt < 6; ++kt) {
                short8 af = *(const short8*)(wr + kt * 32 + hi4 * 8);
                a = __builtin_amdgcn_mfma_f32_16x16x32_bf16(af, bx[kt], a, 0, 0, 0);
            }
            // bias, permutation inlined: section = mt>>1 (0=q,1=k,2=v)
            const int bsrc = (mt >> 1) * 192 + h * 32 + (mt & 1) * 16 + hi4 * 4;
            a[0] += qkv_b[bsrc + 0];
            a[1] += qkv_b[bsrc + 1];
            a[2] += qkv_b[bsrc + 2];
            a[3] += qkv_b[bsrc + 3];
            if (mt < 2) {
                uint2 u; u.x = pkbf(a[0], a[1]); u.y = pkbf(a[2], a[3]);
                *(uint2*)(qo_lds + t * 80 + (mt * 16 + hi4 * 4) * 2) = u;
            } else if (mt < 4) {
                uint2 u; u.x = pkbf(a[0], a[1]); u.y = pkbf(a[2], a[3]);
                *(uint2*)(k_lds + t * 80 + ((mt - 2) * 16 + hi4 * 4) * 2) = u;
            } else {
                const int d0 = (mt - 4) * 16 + hi4 * 4;
                char* vb = v_lds + t * 2;
                *(unsigned short*)(vb + (d0 + 0) * 144) = f2bf(a[0]);
                *(unsigned short*)(vb + (d0 + 1) * 144) = f2bf(a[1]);
                *(unsigned short*)(vb + (d0 + 2) * 144) = f2bf(a[2]);
                *(unsigned short*)(vb + (d0 + 3) * 144) = f2bf(a[3]);
            }
        }
        __syncthreads();

        // ---- scores + softmax: wave handles i-tile = wid ----
        {
            const short8 aq = *(const short8*)(qo_lds + t * 80 + hi4 * 16);
            f32x4 s[4];
            #pragma unroll
            for (int jt = 0; jt < 4; ++jt) {
                const short8 bk = *(const short8*)(k_lds + (jt * 16 + ln) * 80 + hi4 * 16);
                f32x4 z = {0.f, 0.f, 0.f, 0.f};
                s[jt] = __builtin_amdgcn_mfma_f32_16x16x32_bf16(aq, bk, z, 0, 0, 0);
            }
            #pragma unroll
            for (int r = 0; r < 4; ++r) {
                float m = fmaxf(fmaxf(s[0][r], s[1][r]), fmaxf(s[2][r], s[3][r]));
                m = fmaxf(m, __shfl_xor(m, 1));
                m = fmaxf(m, __shfl_xor(m, 2));
                m = fmaxf(m, __shfl_xor(m, 4));
                m = fmaxf(m, __shfl_xor(m, 8));
                float p0 = EXP2F((s[0][r] - m) * SC2);
                float p1 = EXP2F((s[1][r] - m) * SC2);
                float p2 = EXP2F((s[2][r] - m) * SC2);
                float p3 = EXP2F((s[3][r] - m) * SC2);
                float sum = p0 + p1 + p2 + p3;
                sum += __shfl_xor(sum, 1);
                sum += __shfl_xor(sum, 2);
                sum += __shfl_xor(sum, 4);
                sum += __shfl_xor(sum, 8);
                const float rinv = RCPF(sum);
                char* pr = p_lds + (wid * 16 + hi4 * 4 + r) * 144 + ln * 2;
                *(unsigned short*)(pr + 0)  = f2bf(p0 * rinv);
                *(unsigned short*)(pr + 32) = f2bf(p1 * rinv);
                *(unsigned short*)(pr + 64) = f2bf(p2 * rinv);
                *(unsigned short*)(pr + 96) = f2bf(p3 * rinv);
            }
        }
        __syncthreads();

        // ---- PV (swapped: A=vT rows d, B=p rows i -> D[d][i]) ----
        // wave: dt = wid&1, i-tiles {wid>>1, (wid>>1)+2}; o -> qo_lds (aliases dead q)
        {
            const int dt = wid & 1;
            #pragma unroll
            for (int e = 0; e < 2; ++e) {
                const int i0 = ((wid >> 1) + e * 2) * 16;
                f32x4 o = {0.f, 0.f, 0.f, 0.f};
                #pragma unroll
                for (int kc = 0; kc < 2; ++kc) {
                    const short8 av = *(const short8*)(v_lds + (dt * 16 + ln) * 144 + kc * 64 + hi4 * 16);
                    const short8 bp = *(const short8*)(p_lds + (i0 + ln) * 144 + kc * 64 + hi4 * 16);
                    o = __builtin_amdgcn_mfma_f32_16x16x32_bf16(av, bp, o, 0, 0, 0);
                }
                uint2 u; u.x = pkbf(o[0], o[1]); u.y = pkbf(o[2], o[3]);
                *(uint2*)(qo_lds + (i0 + ln) * 80 + (dt * 16 + hi4 * 4) * 2) = u;
            }
        }
        __syncthreads();

        // ---- head-proj partial: acc[c][t] += whc[c][h*32+j] * o[t][j], K=32 ----
        {
            short8 bo[4];
            #pragma unroll
            for (int nt = 0; nt < 4; ++nt)
                bo[nt] = *(const short8*)(qo_lds + (nt * 16 + ln) * 80 + hi4 * 16);
            #pragma unroll
            for (int mm = 0; mm < 3; ++mm) {
                const int c0 = (wid * 3 + mm) * 16;
                const short8 af = *(const short8*)(whc + (c0 + ln) * 192 + h * 32 + hi4 * 8);
                #pragma unroll
                for (int nt = 0; nt < 4; ++nt)
                    acc[mm][nt] = __builtin_amdgcn_mfma_f32_16x16x32_bf16(af, bo[nt], acc[mm][nt], 0, 0, 0);
            }
        }
        __syncthreads();
    }

    // ---- final store: out[c][spatial t] = acc + head_b ----
    #pragma unroll
    for (int mm = 0; mm < 3; ++mm) {
        const int c0 = (wid * 3 + mm) * 16;
        const float4 hb = *(const float4*)(head_b + c0 + hi4 * 4);
        #pragma unroll
        for (int nt = 0; nt < 4; ++nt) {
            const int tt = nt * 16 + ln;
            const int y = tt >> 3, xx = tt & 7;
            float* op = out + ((size_t)(b * 192) * 384 + (row0 + y)) * 384 + (col0 + xx);
            op[(size_t)(c0 + hi4 * 4 + 0) * 147456] = acc[mm][nt][0] + hb.x;
            op[(size_t)(c0 + hi4 * 4 + 1) * 147456] = acc[mm][nt][1] + hb.y;
            op[(size_t)(c0 + hi4 * 4 + 2) * 147456] = acc[mm][nt][2] + hb.z;
            op[(size_t)(c0 + hi4 * 4 + 3) * 147456] = acc[mm][nt][3] + hb.w;
        }
    }
}

extern "C" void kernel_launch(void* const* d_in, const int* in_sizes, int n_in,
                              void* d_out, int out_size, void* d_ws, size_t ws_size,
                              hipStream_t stream) {
    const float* x      = (const float*)d_in[0];
    const float* qkv_w  = (const float*)d_in[1];
    const float* qkv_b  = (const float*)d_in[2];
    const float* head_w = (const float*)d_in[3];
    const float* head_b = (const float*)d_in[4];
    float* out = (float*)d_out;

    unsigned short* wqp = (unsigned short*)d_ws;   // 576*192 ushort = 221184 B
    unsigned short* whc = wqp + 576 * 192;         // 192*192 ushort =  73728 B (total 294912 B, same as round 1)

    cvt_weights<<<432, 256, 0, stream>>>(qkv_w, head_w, wqp, whc);

    hipFuncSetAttribute((const void*)wmha, hipFuncAttributeMaxDynamicSharedMemorySize, LDS_TOTAL);
    wmha<<<9216, 256, LDS_TOTAL, stream>>>(x, qkv_b, head_b, wqp, whc, out);
}

// Round 4
// 564.161 us; speedup vs baseline: 2.1534x; 2.1534x over previous
//
#include <hip/hip_runtime.h>

typedef __attribute__((ext_vector_type(8))) short short8;
typedef __attribute__((ext_vector_type(4))) float f32x4;

#if __has_builtin(__builtin_amdgcn_exp2f)
#define EXP2F(x) __builtin_amdgcn_exp2f(x)
#else
#define EXP2F(x) exp2f(x)
#endif
#if __has_builtin(__builtin_amdgcn_rcpf)
#define RCPF(x) __builtin_amdgcn_rcpf(x)
#else
#define RCPF(x) (1.0f/(x))
#endif

#define SQ 208   // q/k/o row stride (96 bf16 cols + pad, 16B aligned)
#define SV 144   // vT / p row stride (64 bf16 cols + pad, 16B aligned)

// LDS (bytes):
//   x_lds [64][400] @0..25600   (staging; dead after bx preload)
//   q_lds [64][208] @0      13312  (overlays x region after barrier)
//   k_lds [64][208] @13312  13312
//   v_lds [96][144] @26624  13824  (vT per 3-head group: row = hl*32+d, col = t)
//   o_lds [64][208] @40448  13312
//   p_scr [4][16][144] @53760 9216 (per-wave private)
#define LDS_TOTAL 62976

__device__ __forceinline__ unsigned short f2bf(float f) {
    union { float f; unsigned u; } v; v.f = f;
    unsigned r = v.u + 0x7FFFu + ((v.u >> 16) & 1u);
    return (unsigned short)(r >> 16);
}
__device__ __forceinline__ unsigned pkbf(float lo, float hi) {
    return (unsigned)f2bf(lo) | ((unsigned)f2bf(hi) << 16);
}

__global__ void cvt_weights(const float* __restrict__ qw, const float* __restrict__ hw,
                            unsigned short* __restrict__ wq, unsigned short* __restrict__ wh) {
    int i = blockIdx.x * 256 + threadIdx.x;
    if (i < 576 * 192) wq[i] = f2bf(qw[i]);
    if (i < 192 * 192) wh[i] = f2bf(hw[i]);
}

__global__ __launch_bounds__(256, 2) void wmha(
    const float* __restrict__ x, const float* __restrict__ qkv_b,
    const float* __restrict__ head_b, const unsigned short* __restrict__ wq,
    const unsigned short* __restrict__ whc, float* __restrict__ out)
{
    extern __shared__ char smem[];
    char* const x_lds = smem;
    char* const q_lds = smem;
    char* const k_lds = smem + 13312;
    char* const v_lds = smem + 26624;
    char* const o_lds = smem + 40448;

    const int tid = threadIdx.x;
    const int ln  = tid & 15;
    const int hi4 = (tid >> 4) & 3;
    const int wid = tid >> 6;
    char* const p_scr = smem + 53760 + wid * 2304;

    const int bid  = blockIdx.x;
    const int widx = (bid & 7) * 1152 + (bid >> 3);   // bijective XCD swizzle (9216 % 8 == 0)
    const int b  = widx / 2304;
    const int rr = widx % 2304;
    const int oy = rr / 48, ox = rr % 48;
    const int row0 = oy * 8, col0 = ox * 8;

    // ---- stage x window -> x_lds bf16 [t][c], stride 400 ----
    {
        const int tok = tid & 63;
        const int qd  = tid >> 6;
        const int y = tok >> 3, xx = tok & 7;
        const float* gp = x + ((size_t)(b * 192) * 384 + (row0 + y)) * 384 + (col0 + xx);
        char* wp = x_lds + tok * 400 + qd * 96;
        #pragma unroll
        for (int kk = 0; kk < 12; ++kk) {
            const int c = qd * 48 + kk * 4;
            float f0 = gp[(size_t)(c + 0) * 147456];
            float f1 = gp[(size_t)(c + 1) * 147456];
            float f2 = gp[(size_t)(c + 2) * 147456];
            float f3 = gp[(size_t)(c + 3) * 147456];
            uint2 u;
            u.x = pkbf(f0, f1);
            u.y = pkbf(f2, f3);
            *(uint2*)(wp + kk * 8) = u;
        }
    }
    __syncthreads();

    // every wave preloads ALL 4 token-tiles' B-frags (96 VGPR); x_lds dead after
    short8 bx[4][6];
    #pragma unroll
    for (int nt = 0; nt < 4; ++nt)
        #pragma unroll
        for (int kt = 0; kt < 6; ++kt)
            bx[nt][kt] = *(const short8*)(x_lds + (nt * 16 + ln) * 400 + kt * 64 + hi4 * 16);
    __syncthreads();   // x reads done; q/k may overwrite

    // head-proj accumulators (register, never materialized in LDS)
    f32x4 acc[3][4];
    #pragma unroll
    for (int mm = 0; mm < 3; ++mm)
        #pragma unroll
        for (int nt = 0; nt < 4; ++nt)
            acc[mm][nt] = (f32x4){0.f, 0.f, 0.f, 0.f};

    const float SC2 = 0.25503417f;  // (1/sqrt(32)) * log2(e)

    // ---- QKV for 3-head group g: 18 m-tiles split across waves (weights read once/block) ----
    auto qkv = [&](int g) {
        for (int mt = wid; mt < 18; mt += 4) {
            const int hl = mt / 6, sec = (mt % 6) >> 1, e = mt & 1;
            const int r0 = sec * 192 + (3 * g + hl) * 32 + e * 16;
            short8 wf[6];
            #pragma unroll
            for (int kt = 0; kt < 6; ++kt)
                wf[kt] = *(const short8*)(wq + (r0 + ln) * 192 + kt * 32 + hi4 * 8);
            if (sec < 2) {
                // D[d][t] = W x^T : rows d = hi4*4+r, col t = ln  -> packed [t][d] store
                char* dst = (sec == 0) ? q_lds : k_lds;
                const float4 bias = *(const float4*)(qkv_b + r0 + hi4 * 4);
                #pragma unroll
                for (int nt = 0; nt < 4; ++nt) {
                    f32x4 a = {0.f, 0.f, 0.f, 0.f};
                    #pragma unroll
                    for (int kt = 0; kt < 6; ++kt)
                        a = __builtin_amdgcn_mfma_f32_16x16x32_bf16(wf[kt], bx[nt][kt], a, 0, 0, 0);
                    uint2 u;
                    u.x = pkbf(a[0] + bias.x, a[1] + bias.y);
                    u.y = pkbf(a[2] + bias.z, a[3] + bias.w);
                    *(uint2*)(dst + (nt * 16 + ln) * SQ + hl * 64 + (e * 16 + hi4 * 4) * 2) = u;
                }
            } else {
                // swapped: D[t][d] = x W^T : rows t = hi4*4+r, col d = ln -> packed vT[d][t] store
                const float bv = qkv_b[r0 + ln];
                #pragma unroll
                for (int nt = 0; nt < 4; ++nt) {
                    f32x4 a = {0.f, 0.f, 0.f, 0.f};
                    #pragma unroll
                    for (int kt = 0; kt < 6; ++kt)
                        a = __builtin_amdgcn_mfma_f32_16x16x32_bf16(bx[nt][kt], wf[kt], a, 0, 0, 0);
                    uint2 u;
                    u.x = pkbf(a[0] + bv, a[1] + bv);
                    u.y = pkbf(a[2] + bv, a[3] + bv);
                    *(uint2*)(v_lds + (hl * 32 + e * 16 + ln) * SV + (nt * 16 + hi4 * 4) * 2) = u;
                }
            }
        }
    };

    // ---- attention: 12 units (3 heads x 4 i-tiles) / 4 waves; scores swapped -> in-lane softmax ----
    auto attn = [&](int g) {
        #pragma unroll
        for (int uu = 0; uu < 3; ++uu) {
            const int u = wid + uu * 4;
            const int hl = u >> 2, i0 = (u & 3) * 16;
            const short8 bq = *(const short8*)(q_lds + (i0 + ln) * SQ + hl * 64 + hi4 * 16);
            f32x4 s[4];
            #pragma unroll
            for (int kt = 0; kt < 4; ++kt) {
                const short8 ak = *(const short8*)(k_lds + (kt * 16 + ln) * SQ + hl * 64 + hi4 * 16);
                f32x4 z = {0.f, 0.f, 0.f, 0.f};
                s[kt] = __builtin_amdgcn_mfma_f32_16x16x32_bf16(ak, bq, z, 0, 0, 0);
            }
            // lane holds S[k = kt*16+hi4*4+r][i = i0+ln]: 16 values of row i
            float m = s[0][0];
            #pragma unroll
            for (int kt = 0; kt < 4; ++kt)
                #pragma unroll
                for (int r = 0; r < 4; ++r) m = fmaxf(m, s[kt][r]);
            m = fmaxf(m, __shfl_xor(m, 16));
            m = fmaxf(m, __shfl_xor(m, 32));
            float pr[4][4];
            float sum = 0.f;
            #pragma unroll
            for (int kt = 0; kt < 4; ++kt)
                #pragma unroll
                for (int r = 0; r < 4; ++r) {
                    pr[kt][r] = EXP2F((s[kt][r] - m) * SC2);
                    sum += pr[kt][r];
                }
            sum += __shfl_xor(sum, 16);
            sum += __shfl_xor(sum, 32);
            const float rinv = RCPF(sum);
            // packed P store: row i-local = ln, cols j = kt*16+hi4*4+0..3 (8B each)
            #pragma unroll
            for (int kt = 0; kt < 4; ++kt) {
                uint2 u2;
                u2.x = pkbf(pr[kt][0] * rinv, pr[kt][1] * rinv);
                u2.y = pkbf(pr[kt][2] * rinv, pr[kt][3] * rinv);
                *(uint2*)(p_scr + ln * SV + kt * 32 + hi4 * 8) = u2;
            }
            // PV swapped: D[d][i] = vT P^T ; B-frag = P rows i (same-wave read, lgkm only)
            short8 pf[2];
            #pragma unroll
            for (int kc = 0; kc < 2; ++kc)
                pf[kc] = *(const short8*)(p_scr + ln * SV + kc * 64 + hi4 * 16);
            #pragma unroll
            for (int dt = 0; dt < 2; ++dt) {
                f32x4 o = {0.f, 0.f, 0.f, 0.f};
                #pragma unroll
                for (int kc = 0; kc < 2; ++kc) {
                    const short8 av = *(const short8*)(v_lds + (hl * 32 + dt * 16 + ln) * SV + kc * 64 + hi4 * 16);
                    o = __builtin_amdgcn_mfma_f32_16x16x32_bf16(av, pf[kc], o, 0, 0, 0);
                }
                uint2 u2;
                u2.x = pkbf(o[0], o[1]);
                u2.y = pkbf(o[2], o[3]);
                *(uint2*)(o_lds + (i0 + ln) * SQ + hl * 64 + (dt * 16 + hi4 * 4) * 2) = u2;
            }
        }
    };

    // ---- head-proj partial for group g: acc[c][t] += whc[c][g*96..] * o[t][..] ----
    auto proj = [&](int g) {
        short8 bo[4][3];
        #pragma unroll
        for (int nt = 0; nt < 4; ++nt)
            #pragma unroll
            for (int kt = 0; kt < 3; ++kt)
                bo[nt][kt] = *(const short8*)(o_lds + (nt * 16 + ln) * SQ + kt * 64 + hi4 * 16);
        #pragma unroll
        for (int mm = 0; mm < 3; ++mm) {
            const int c0 = (wid * 3 + mm) * 16;
            short8 af[3];
            #pragma unroll
            for (int kt = 0; kt < 3; ++kt)
                af[kt] = *(const short8*)(whc + (c0 + ln) * 192 + g * 96 + kt * 32 + hi4 * 8);
            #pragma unroll
            for (int nt = 0; nt < 4; ++nt)
                #pragma unroll
                for (int kt = 0; kt < 3; ++kt)
                    acc[mm][nt] = __builtin_amdgcn_mfma_f32_16x16x32_bf16(af[kt], bo[nt][kt], acc[mm][nt], 0, 0, 0);
        }
    };

    qkv(0);
    __syncthreads();
    attn(0);
    __syncthreads();
    proj(0);
    qkv(1);          // fused with proj(0): disjoint buffers, no barrier needed
    __syncthreads();
    attn(1);
    __syncthreads();
    proj(1);

    // ---- final store: out[c][spatial t] = acc + head_b ----
    #pragma unroll
    for (int mm = 0; mm < 3; ++mm) {
        const int c0 = (wid * 3 + mm) * 16;
        const float4 hb = *(const float4*)(head_b + c0 + hi4 * 4);
        #pragma unroll
        for (int nt = 0; nt < 4; ++nt) {
            const int tt = nt * 16 + ln;
            const int y = tt >> 3, xx = tt & 7;
            float* op = out + ((size_t)(b * 192) * 384 + (row0 + y)) * 384 + (col0 + xx);
            op[(size_t)(c0 + hi4 * 4 + 0) * 147456] = acc[mm][nt][0] + hb.x;
            op[(size_t)(c0 + hi4 * 4 + 1) * 147456] = acc[mm][nt][1] + hb.y;
            op[(size_t)(c0 + hi4 * 4 + 2) * 147456] = acc[mm][nt][2] + hb.z;
            op[(size_t)(c0 + hi4 * 4 + 3) * 147456] = acc[mm][nt][3] + hb.w;
        }
    }
}

extern "C" void kernel_launch(void* const* d_in, const int* in_sizes, int n_in,
                              void* d_out, int out_size, void* d_ws, size_t ws_size,
                              hipStream_t stream) {
    const float* x      = (const float*)d_in[0];
    const float* qkv_w  = (const float*)d_in[1];
    const float* qkv_b  = (const float*)d_in[2];
    const float* head_w = (const float*)d_in[3];
    const float* head_b = (const float*)d_in[4];
    float* out = (float*)d_out;

    unsigned short* wq  = (unsigned short*)d_ws;   // 576*192 ushort
    unsigned short* whc = wq + 576 * 192;          // 192*192 ushort

    cvt_weights<<<432, 256, 0, stream>>>(qkv_w, head_w, wq, whc);

    hipFuncSetAttribute((const void*)wmha, hipFuncAttributeMaxDynamicSharedMemorySize, LDS_TOTAL);
    wmha<<<9216, 256, LDS_TOTAL, stream>>>(x, qkv_b, head_b, wq, whc, out);
}